// Round 10
// baseline (299.754 us; speedup 1.0000x reference)
//
#include <hip/hip_runtime.h>
#include <cstddef>
#include <cstdint>

// Problem constants (B,T,D fixed by the reference).
#define B_ 8
#define T_ 4096
#define D_ 1024
#define M_ (B_*T_)        // 32768 rows
#define K_ 1024
#define NC 32             // scan chunks per sequence
#define CL 128            // steps per chunk

// GEMM tile config: 256x128 output tile, dual-B (r and i), BK=64, 8 waves.
#define BM 256
#define BN 128

typedef __bf16 bf16x8 __attribute__((ext_vector_type(8)));
typedef float  f32x4  __attribute__((ext_vector_type(4)));

__device__ __forceinline__ void gload_lds16(const __bf16* g, __bf16* l) {
    __builtin_amdgcn_global_load_lds(
        (const __attribute__((address_space(1))) void*)g,
        (__attribute__((address_space(3))) void*)l, 16, 0, 0);
}

__device__ __forceinline__ float bfbits2f(uint32_t hi16_as_low) {
    return __builtin_bit_cast(float, hi16_as_low);
}

// ---------------------------------------------------------------------------
// cvt_all: one launch converting X, Wa, Wx. fp32 [rows][1024] -> bf16, 16
// k-chunks of 64 cols, 128B rows, XOR-swizzled byte ^= (row&7)<<4 (G21
// inverse-swizzled source; linear gl_lds dest; same XOR on ds_read).
// Zero bank conflicts verified (R2/R3).
// ---------------------------------------------------------------------------
__global__ __launch_bounds__(256) void cvt_all(
    const float* __restrict__ X, const float* __restrict__ Wa,
    const float* __restrict__ Wx, __bf16* __restrict__ Xsw,
    __bf16* __restrict__ Wasw, __bf16* __restrict__ Wxsw)
{
    int bb = blockIdx.x;
    const float* src; __bf16* dst; int rows;
    if (bb < M_ / 2)            { src = X;  dst = Xsw;  rows = M_;   }
    else if (bb < M_ / 2 + 512) { src = Wa; dst = Wasw; rows = 1024; bb -= M_ / 2; }
    else                        { src = Wx; dst = Wxsw; rows = 1024; bb -= M_ / 2 + 512; }

    const int g  = bb * 256 + threadIdx.x;           // rows*128 threads
    const int r  = g >> 7;
    const int k0 = (g & 127) << 3;                   // 8 elems per thread
    const int kc = k0 >> 6;
    const int jj = k0 & 63;
    const float4 v0 = *reinterpret_cast<const float4*>(src + (size_t)r * 1024 + k0);
    const float4 v1 = *reinterpret_cast<const float4*>(src + (size_t)r * 1024 + k0 + 4);
    bf16x8 s;
    s[0]=(__bf16)v0.x; s[1]=(__bf16)v0.y; s[2]=(__bf16)v0.z; s[3]=(__bf16)v0.w;
    s[4]=(__bf16)v1.x; s[5]=(__bf16)v1.y; s[6]=(__bf16)v1.z; s[7]=(__bf16)v1.w;
    const uint32_t inrow = (uint32_t)(r * 128 + (jj << 1)) ^ (uint32_t)((r & 7) << 4);
    const size_t byteoff = (size_t)kc * ((size_t)rows * 128) + inrow;
    *reinterpret_cast<bf16x8*>(reinterpret_cast<char*>(dst) + byteoff) = s;
}

// ---------------------------------------------------------------------------
// K1: fused dual-GEMM + slim gate epilogue. R3-verbatim main loop (dbuf,
// counted vmcnt(8), 2 barriers/chunk — measured best of 6 schedule variants:
// 183 vs 190/206/209/219/233 µs). zr=x@Wa^T+ba, zi=x@Wx^T+bx; r=sig(zr),
// i=sig(zi); e=8*r*log2(sig(lambda)); stores packed dword
// {lo: bf16(e), hi: bf16(i*x)}. a/gate reconstruction deferred to the
// BW-bound scan kernels (free VALU there). Epilogue reads X fp32 directly
// (64B-coalesced, L3-resident) instead of the 2B swizzled Xsw gather.
// ---------------------------------------------------------------------------
__global__ __launch_bounds__(512, 1) void rg_gemm_gate(
    const float* __restrict__ Xf,
    const __bf16* __restrict__ Xsw, const __bf16* __restrict__ Wasw,
    const __bf16* __restrict__ Wxsw, const float* __restrict__ Ba,
    const float* __restrict__ Bx, const float* __restrict__ LL,
    uint32_t* __restrict__ EIX)
{
    __shared__ __bf16 Al [2][BM * 64];   // 64 KiB
    __shared__ __bf16 Brs[2][BN * 64];   // 32 KiB
    __shared__ __bf16 Bis[2][BN * 64];   // 32 KiB

    const int tid  = threadIdx.x;
    const int lane = tid & 63;
    const int w    = tid >> 6;           // 8 waves: 4M x 2N
    const int wr   = (w >> 1) * 64;
    const int wc   = (w & 1) * 64;

    // XCD swizzle (1024 blocks, %8==0): n-tile fastest within each XCD.
    const int bid  = blockIdx.x;
    const int wgid = (bid & 7) * 128 + (bid >> 3);
    const int n0   = (wgid & 7) << 7;    // 8 n-tiles
    const int m0   = (wgid >> 3) << 8;   // 128 m-tiles

    const int lrow = lane & 15;
    const int lkb  = (lane >> 4) << 4;   // byte offset of k-fragment in row

    f32x4 accr[4][4] = {};
    f32x4 acci[4][4] = {};

    // Per-wave stage = 8 global_load_lds (A:4, Br:2, Bi:2), 1 KiB each.
    auto STAGE = [&](int buf, int kc) {
        const size_t cbA = (size_t)kc * ((size_t)M_ * 64) + (size_t)m0 * 64;
        const size_t cbB = (size_t)kc * (1024 * 64) + (size_t)n0 * 64;
        #pragma unroll
        for (int c = 0; c < 4; ++c) {
            const int j = (c * 8 + w) * 512;
            gload_lds16(Xsw + cbA + j + lane * 8, &Al[buf][j]);
        }
        #pragma unroll
        for (int c = 0; c < 2; ++c) {
            const int j = (c * 8 + w) * 512;
            gload_lds16(Wasw + cbB + j + lane * 8, &Brs[buf][j]);
            gload_lds16(Wxsw + cbB + j + lane * 8, &Bis[buf][j]);
        }
    };

    STAGE(0, 0);
    for (int kc = 0; kc < 16; ++kc) {
        const int cur = kc & 1;
        if (kc < 15) {
            STAGE(cur ^ 1, kc + 1);
            asm volatile("s_waitcnt vmcnt(8)" ::: "memory");  // buf[cur] landed; next 8 in flight
        } else {
            asm volatile("s_waitcnt vmcnt(0)" ::: "memory");
        }
        __builtin_amdgcn_s_barrier();

        const char* Ab = reinterpret_cast<const char*>(Al[cur]);
        const char* Rb = reinterpret_cast<const char*>(Brs[cur]);
        const char* Ib = reinterpret_cast<const char*>(Bis[cur]);
        #pragma unroll
        for (int ks = 0; ks < 2; ++ks) {
            bf16x8 af[4], brf[4], bif[4];
            #pragma unroll
            for (int mi = 0; mi < 4; ++mi) {
                const int ra = wr + mi * 16 + lrow;
                const uint32_t bo = (uint32_t)(ra * 128 + ks * 64 + lkb)
                                  ^ (uint32_t)((ra & 7) << 4);
                af[mi] = *reinterpret_cast<const bf16x8*>(Ab + bo);
            }
            #pragma unroll
            for (int ni = 0; ni < 4; ++ni) {
                const int rb = wc + ni * 16 + lrow;
                const uint32_t bo = (uint32_t)(rb * 128 + ks * 64 + lkb)
                                  ^ (uint32_t)((rb & 7) << 4);
                brf[ni] = *reinterpret_cast<const bf16x8*>(Rb + bo);
                bif[ni] = *reinterpret_cast<const bf16x8*>(Ib + bo);
            }
            #pragma unroll
            for (int mi = 0; mi < 4; ++mi) {
                #pragma unroll
                for (int ni = 0; ni < 4; ++ni) {
                    accr[mi][ni] = __builtin_amdgcn_mfma_f32_16x16x32_bf16(
                        af[mi], brf[ni], accr[mi][ni], 0, 0, 0);
                    acci[mi][ni] = __builtin_amdgcn_mfma_f32_16x16x32_bf16(
                        af[mi], bif[ni], acci[mi][ni], 0, 0, 0);
                }
            }
        }
        __builtin_amdgcn_s_barrier();
    }

    // ---- epilogue: C/D layout col = lane&15, row = (lane>>4)*4 + j ----
    const int rbase = m0 + wr + ((lane >> 4) << 2);
    const int cbase = n0 + wc + lrow;
    #pragma unroll
    for (int ni = 0; ni < 4; ++ni) {
        const int col = cbase + ni * 16;
        const float lam = LL[col];
        const float l2s = -log2f(1.0f + __expf(-lam));  // log2(sigmoid(lambda))
        const float bav = Ba[col];
        const float bxv = Bx[col];
        #pragma unroll
        for (int mi = 0; mi < 4; ++mi) {
            #pragma unroll
            for (int j = 0; j < 4; ++j) {
                const int row = rbase + mi * 16 + j;
                const size_t idx = (size_t)row * D_ + col;
                const float zr = accr[mi][ni][j] + bav;
                const float zi = acci[mi][ni][j] + bxv;
                const float rv = 1.0f / (1.0f + __expf(-zr));
                const float iv = 1.0f / (1.0f + __expf(-zi));
                const float ee = 8.0f * rv * l2s;       // log2(a)
                const float ixv = iv * Xf[idx];
                const uint16_t ebits  = __builtin_bit_cast(uint16_t, (__bf16)ee);
                const uint16_t ixbits = __builtin_bit_cast(uint16_t, (__bf16)ixv);
                EIX[idx] = (uint32_t)ebits | ((uint32_t)ixbits << 16);
            }
        }
    }
}

// ---------------------------------------------------------------------------
// K2: per-chunk summaries: P = prod a = 2^(sum e), hend = local scan from 0.
// ---------------------------------------------------------------------------
__global__ __launch_bounds__(256) void rg_scan_chunks(
    const uint32_t* __restrict__ EIX, float* __restrict__ P, float* __restrict__ HE)
{
    const int g = blockIdx.x * 256 + threadIdx.x;   // < B*NC*D = 262144
    const int d = g & (D_ - 1);
    const int c = (g >> 10) & (NC - 1);
    const int b = g >> 15;
    const size_t base = ((size_t)(b * T_ + c * CL)) * D_ + d;

    float h = 0.0f;
    float se = 0.0f;
    #pragma unroll 8
    for (int t = 0; t < CL; ++t) {
        const uint32_t u = EIX[base + (size_t)t * D_];
        const float e  = bfbits2f(u << 16);
        const float ix = bfbits2f(u & 0xffff0000u);
        const float a  = exp2f(e);
        const float gate = sqrtf(fmaxf((1.0f - a) * (1.0f + a), 1e-6f));
        h = fmaf(a, h, gate * ix);
        se += e;
    }
    const int sidx = (b * NC + c) * D_ + d;
    P[sidx]  = exp2f(se);
    HE[sidx] = h;
}

// ---------------------------------------------------------------------------
// K3: sequential combine over NC chunks per (b,d); seeds with h0.
// ---------------------------------------------------------------------------
__global__ __launch_bounds__(256) void rg_combine(
    const float* __restrict__ P, const float* __restrict__ HE,
    const float* __restrict__ H0, float* __restrict__ CI,
    float* __restrict__ HF)
{
    const int g = blockIdx.x * 256 + threadIdx.x;   // < B*D = 8192
    const int d = g & (D_ - 1);
    const int b = g >> 10;
    float carry = H0[g];
    #pragma unroll
    for (int c = 0; c < NC; ++c) {
        const int sidx = (b * NC + c) * D_ + d;
        CI[sidx] = carry;
        carry = fmaf(P[sidx], carry, HE[sidx]);
    }
    HF[g] = carry;
}

// ---------------------------------------------------------------------------
// K4: final intra-chunk scan with correct carry; writes h_t to OUT (write-only).
// ---------------------------------------------------------------------------
__global__ __launch_bounds__(256) void rg_scan_final(
    const uint32_t* __restrict__ EIX, const float* __restrict__ CI,
    float* __restrict__ OUT)
{
    const int g = blockIdx.x * 256 + threadIdx.x;   // < B*NC*D
    const int d = g & (D_ - 1);
    const int c = (g >> 10) & (NC - 1);
    const int b = g >> 15;
    const size_t base = ((size_t)(b * T_ + c * CL)) * D_ + d;

    float h = CI[(b * NC + c) * D_ + d];
    #pragma unroll 8
    for (int t = 0; t < CL; ++t) {
        const size_t idx = base + (size_t)t * D_;
        const uint32_t u = EIX[idx];
        const float e  = bfbits2f(u << 16);
        const float ix = bfbits2f(u & 0xffff0000u);
        const float a  = exp2f(e);
        const float gate = sqrtf(fmaxf((1.0f - a) * (1.0f + a), 1e-6f));
        h = fmaf(a, h, gate * ix);
        OUT[idx] = h;
    }
}

// ---------------------------------------------------------------------------
extern "C" void kernel_launch(void* const* d_in, const int* in_sizes, int n_in,
                              void* d_out, int out_size, void* d_ws, size_t ws_size,
                              hipStream_t stream)
{
    (void)in_sizes; (void)n_in; (void)out_size; (void)ws_size;
    const float* X  = (const float*)d_in[0];
    const float* H0 = (const float*)d_in[1];
    const float* Wa = (const float*)d_in[2];
    const float* Ba = (const float*)d_in[3];
    const float* Wx = (const float*)d_in[4];
    const float* Bx = (const float*)d_in[5];
    const float* LL = (const float*)d_in[6];

    // d_out doubles as scratch for the bf16-converted operands (dead before K4
    // rewrites every output element):
    //   [0,64MB)    Xsw   (bf16, swizzled 64-col k-chunked)
    //   [64,66MB)   Wasw  [66,68MB) Wxsw
    char* ob = (char*)d_out;
    __bf16* Xsw  = (__bf16*)ob;
    __bf16* Wasw = (__bf16*)(ob + ((size_t)M_ * K_ * 2));
    __bf16* Wxsw = (__bf16*)(ob + ((size_t)M_ * K_ * 2) + (size_t)K_ * D_ * 2);
    float*  OUT  = (float*)d_out;
    float*  HFINAL = OUT + (size_t)M_ * D_;    // h_final after outputs

    // ws: EIX (uint32, 128MB) | P | HE | CI (1MB each)  = 131 MB
    char* ws = (char*)d_ws;
    uint32_t* EIX = (uint32_t*)ws;
    float* P  = (float*)(ws + (size_t)M_ * D_ * 4);
    float* HE = P  + (size_t)B_ * NC * D_;
    float* CI = HE + (size_t)B_ * NC * D_;

    cvt_all<<<dim3(M_ / 2 + 1024), dim3(256), 0, stream>>>(
        X, Wa, Wx, Xsw, Wasw, Wxsw);

    rg_gemm_gate<<<dim3((M_/BM) * (D_/BN)), dim3(512), 0, stream>>>(
        X, Xsw, Wasw, Wxsw, Ba, Bx, LL, EIX);

    rg_scan_chunks<<<dim3(B_ * NC * D_ / 256), dim3(256), 0, stream>>>(EIX, P, HE);
    rg_combine<<<dim3(B_ * D_ / 256), dim3(256), 0, stream>>>(P, HE, H0, CI, HFINAL);
    rg_scan_final<<<dim3(B_ * NC * D_ / 256), dim3(256), 0, stream>>>(EIX, CI, OUT);
}

// Round 11
// 274.531 us; speedup vs baseline: 1.0919x; 1.0919x over previous
//
#include <hip/hip_runtime.h>
#include <cstddef>
#include <cstdint>

// Problem constants (B,T,D fixed by the reference).
#define B_ 8
#define T_ 4096
#define D_ 1024
#define M_ (B_*T_)        // 32768 rows
#define K_ 1024
#define NC 32             // scan chunks per sequence
#define CL 128            // steps per chunk

// GEMM tile config: 256x128 output tile, dual-B (r and i), BK=64, 8 waves.
#define BM 256
#define BN 128

typedef __bf16 bf16x8 __attribute__((ext_vector_type(8)));
typedef float  f32x16 __attribute__((ext_vector_type(16)));

__device__ __forceinline__ void gload_lds16(const __bf16* g, __bf16* l) {
    __builtin_amdgcn_global_load_lds(
        (const __attribute__((address_space(1))) void*)g,
        (__attribute__((address_space(3))) void*)l, 16, 0, 0);
}

__device__ __forceinline__ float bfbits2f(uint32_t hi16_as_low) {
    return __builtin_bit_cast(float, hi16_as_low);
}

// ---------------------------------------------------------------------------
// cvt_frag: fp32 [rows][1024] -> bf16 in FRAGMENT-MAJOR k-chunk layout:
// per 64-col k-chunk: [rowgrp(rows/32)][ksub(4)][khalf(2)][row32(32)][8xbf16].
// A wave's 32x32x16 fragment read is then a contiguous 1KB block (lane-linear)
// -> conflict-free by construction (same pattern as gl_lds staging).
// Both global sides coalesced via a 32x129-padded LDS transpose tile.
// ---------------------------------------------------------------------------
__global__ __launch_bounds__(256) void cvt_frag(
    const float* __restrict__ X, const float* __restrict__ Wa,
    const float* __restrict__ Wx, __bf16* __restrict__ Xsw,
    __bf16* __restrict__ Wasw, __bf16* __restrict__ Wxsw)
{
    __shared__ float tile[32][129];      // +1 dword pad: r-major reads spread banks

    int bb = blockIdx.x;                 // X: 8192 tiles; Wa: 256; Wx: 256
    const float* src; __bf16* dst; int rows;
    if (bb < 8192)            { src = X;  dst = Xsw;  rows = M_;   }
    else if (bb < 8192 + 256) { src = Wa; dst = Wasw; rows = 1024; bb -= 8192; }
    else                      { src = Wx; dst = Wxsw; rows = 1024; bb -= 8448; }

    const int tr = bb >> 3;              // 32-row band
    const int tk = bb & 7;               // 128-col band (2 k-chunks)
    const int r0 = tr * 32, kb = tk * 128;
    const int tid = threadIdx.x;

    // load 32x128 fp32 tile, coalesced (8 threads/row x 16 floats)
    {
        const int r  = tid >> 3;
        const int ko = (tid & 7) * 16;
        const float* s = src + (size_t)(r0 + r) * 1024 + kb + ko;
        #pragma unroll
        for (int q = 0; q < 4; ++q) {
            const float4 v = *reinterpret_cast<const float4*>(s + q * 4);
            tile[r][ko + q * 4 + 0] = v.x; tile[r][ko + q * 4 + 1] = v.y;
            tile[r][ko + q * 4 + 2] = v.z; tile[r][ko + q * 4 + 3] = v.w;
        }
    }
    __syncthreads();

    // write dest-linear: 512 16B-slots; slot s: [kc_l][ksub][khalf][r32]
    #pragma unroll
    for (int it = 0; it < 2; ++it) {
        const int s    = tid + it * 256;
        const int kc_l = s >> 8;
        const int rem  = s & 255;        // = ksub*64 + khalf*32 + r32 (dest-linear)
        const int ksub = rem >> 6;
        const int khalf= (rem >> 5) & 1;
        const int r32  = rem & 31;
        const int kk   = kc_l * 64 + ksub * 16 + khalf * 8;
        bf16x8 o;
        #pragma unroll
        for (int j = 0; j < 8; ++j) o[j] = (__bf16)tile[r32][kk + j];
        const int kc = (kb >> 6) + kc_l;
        char* d = reinterpret_cast<char*>(dst)
                + (size_t)kc * ((size_t)rows * 128)
                + (size_t)tr * 4096 + (size_t)rem * 16;
        *reinterpret_cast<bf16x8*>(d) = o;
    }
}

// ---------------------------------------------------------------------------
// K1: fused dual-GEMM + slim gate epilogue. R3-exact schedule (dbuf, counted
// vmcnt(8), 2 barriers/chunk — best of 7 variants) with 32x32x16 MFMA (half
// the MFMA instructions, m119 +15% rate) on fragment-major LDS (contiguous
// 1KB fragment reads, conflict-free by construction; fixes R7's 12.6M).
// zr=x@Wa^T+ba, zi=x@Wx^T+bx; r=sig(zr), i=sig(zi); e=8*r*log2(sig(lambda));
// stores packed dword {lo: bf16(e), hi: bf16(i*x)}. Epilogue x from Xsw
// (L2-hot: the block's own staged A-panel covers it; R10 proved fp32-X worse).
// ---------------------------------------------------------------------------
__global__ __launch_bounds__(512, 1) void rg_gemm_gate(
    const __bf16* __restrict__ Xsw, const __bf16* __restrict__ Wasw,
    const __bf16* __restrict__ Wxsw, const float* __restrict__ Ba,
    const float* __restrict__ Bx, const float* __restrict__ LL,
    uint32_t* __restrict__ EIX)
{
    __shared__ __bf16 Al [2][BM * 64];   // 64 KiB
    __shared__ __bf16 Brs[2][BN * 64];   // 32 KiB
    __shared__ __bf16 Bis[2][BN * 64];   // 32 KiB

    const int tid  = threadIdx.x;
    const int lane = tid & 63;
    const int w    = tid >> 6;           // 8 waves: 4M x 2N
    const int wr   = (w >> 1) * 64;
    const int wc   = (w & 1) * 64;
    const int l31  = lane & 31;
    const int lhalf= lane >> 5;

    // XCD swizzle (1024 blocks, %8==0): n-tile fastest within each XCD.
    const int bid  = blockIdx.x;
    const int wgid = (bid & 7) * 128 + (bid >> 3);
    const int n0   = (wgid & 7) << 7;    // 8 n-tiles
    const int m0   = (wgid >> 3) << 8;   // 128 m-tiles

    // Fragment read offset: contiguous 1KB per (rowgrp, ksub); lane-linear.
    const uint32_t lfrag = ((uint32_t)lhalf << 9) | ((uint32_t)l31 << 4);
    const uint32_t argA  = (uint32_t)(wr >> 5) << 12;   // rowgrp * 4096
    const uint32_t argB  = (uint32_t)(wc >> 5) << 12;

    f32x16 accr[2][2] = {};
    f32x16 acci[2][2] = {};

    // Per-wave stage = 8 global_load_lds (A:4, Br:2, Bi:2), 1 KiB each.
    // (byte-identical to R3: panels are linear 32KB/16KB blocks per k-chunk)
    auto STAGE = [&](int buf, int kc) {
        const size_t cbA = (size_t)kc * ((size_t)M_ * 64) + (size_t)m0 * 64;
        const size_t cbB = (size_t)kc * (1024 * 64) + (size_t)n0 * 64;
        #pragma unroll
        for (int c = 0; c < 4; ++c) {
            const int j = (c * 8 + w) * 512;
            gload_lds16(Xsw + cbA + j + lane * 8, &Al[buf][j]);
        }
        #pragma unroll
        for (int c = 0; c < 2; ++c) {
            const int j = (c * 8 + w) * 512;
            gload_lds16(Wasw + cbB + j + lane * 8, &Brs[buf][j]);
            gload_lds16(Wxsw + cbB + j + lane * 8, &Bis[buf][j]);
        }
    };

    STAGE(0, 0);
    for (int kc = 0; kc < 16; ++kc) {
        const int cur = kc & 1;
        if (kc < 15) {
            STAGE(cur ^ 1, kc + 1);
            asm volatile("s_waitcnt vmcnt(8)" ::: "memory");  // buf[cur] landed; next 8 in flight
        } else {
            asm volatile("s_waitcnt vmcnt(0)" ::: "memory");
        }
        __builtin_amdgcn_s_barrier();

        const char* Ab = reinterpret_cast<const char*>(Al[cur]);
        const char* Rb = reinterpret_cast<const char*>(Brs[cur]);
        const char* Ib = reinterpret_cast<const char*>(Bis[cur]);

        #pragma unroll
        for (int ksub = 0; ksub < 4; ++ksub) {
            const uint32_t ko = (uint32_t)ksub << 10;
            bf16x8 af[2], brf[2], bif[2];
            #pragma unroll
            for (int mf = 0; mf < 2; ++mf)
                af[mf] = *reinterpret_cast<const bf16x8*>(
                    Ab + argA + mf * 4096 + ko + lfrag);
            #pragma unroll
            for (int nf = 0; nf < 2; ++nf) {
                brf[nf] = *reinterpret_cast<const bf16x8*>(
                    Rb + argB + nf * 4096 + ko + lfrag);
                bif[nf] = *reinterpret_cast<const bf16x8*>(
                    Ib + argB + nf * 4096 + ko + lfrag);
            }
            #pragma unroll
            for (int mf = 0; mf < 2; ++mf) {
                #pragma unroll
                for (int nf = 0; nf < 2; ++nf) {
                    accr[mf][nf] = __builtin_amdgcn_mfma_f32_32x32x16_bf16(
                        af[mf], brf[nf], accr[mf][nf], 0, 0, 0);
                    acci[mf][nf] = __builtin_amdgcn_mfma_f32_32x32x16_bf16(
                        af[mf], bif[nf], acci[mf][nf], 0, 0, 0);
                }
            }
        }
        __builtin_amdgcn_s_barrier();
    }

    // ---- epilogue: 32x32 C/D layout (m74/m101, R7-verified): col = lane&31,
    // row = (reg&3) + 8*(reg>>2) + 4*(lane>>5). x gathered from frag-major Xsw.
    #pragma unroll
    for (int nf = 0; nf < 2; ++nf) {
        const int col = n0 + wc + nf * 32 + l31;
        const float lam = LL[col];
        const float l2s = -log2f(1.0f + __expf(-lam));  // log2(sigmoid(lambda))
        const float bav = Ba[col];
        const float bxv = Bx[col];
        const int kk  = col & 63;
        const size_t xcol = (size_t)(col >> 6) * ((size_t)M_ * 128)
                          + (size_t)((kk >> 4) * 1024 + ((kk >> 3) & 1) * 512
                                     + (kk & 7) * 2);
        #pragma unroll
        for (int mf = 0; mf < 2; ++mf) {
            const int rb0 = m0 + wr + mf * 32 + 4 * lhalf;
            #pragma unroll
            for (int reg = 0; reg < 16; ++reg) {
                const int row = rb0 + (reg & 3) + 8 * (reg >> 2);
                const float zr = accr[mf][nf][reg] + bav;
                const float zi = acci[mf][nf][reg] + bxv;
                const float rv = 1.0f / (1.0f + __expf(-zr));
                const float iv = 1.0f / (1.0f + __expf(-zi));
                const float ee = 8.0f * rv * l2s;       // log2(a)
                const char* xp = reinterpret_cast<const char*>(Xsw) + xcol
                               + (size_t)(row >> 5) * 4096 + (size_t)(row & 31) * 16;
                const uint16_t xb = *reinterpret_cast<const uint16_t*>(xp);
                const float xv  = bfbits2f((uint32_t)xb << 16);
                const float ixv = iv * xv;
                const uint16_t ebits  = __builtin_bit_cast(uint16_t, (__bf16)ee);
                const uint16_t ixbits = __builtin_bit_cast(uint16_t, (__bf16)ixv);
                EIX[(size_t)row * D_ + col] = (uint32_t)ebits | ((uint32_t)ixbits << 16);
            }
        }
    }
}

// ---------------------------------------------------------------------------
// K2: per-chunk summaries: P = prod a = 2^(sum e), hend = local scan from 0.
// ---------------------------------------------------------------------------
__global__ __launch_bounds__(256) void rg_scan_chunks(
    const uint32_t* __restrict__ EIX, float* __restrict__ P, float* __restrict__ HE)
{
    const int g = blockIdx.x * 256 + threadIdx.x;   // < B*NC*D = 262144
    const int d = g & (D_ - 1);
    const int c = (g >> 10) & (NC - 1);
    const int b = g >> 15;
    const size_t base = ((size_t)(b * T_ + c * CL)) * D_ + d;

    float h = 0.0f;
    float se = 0.0f;
    #pragma unroll 8
    for (int t = 0; t < CL; ++t) {
        const uint32_t u = EIX[base + (size_t)t * D_];
        const float e  = bfbits2f(u << 16);
        const float ix = bfbits2f(u & 0xffff0000u);
        const float a  = exp2f(e);
        const float gate = sqrtf(fmaxf((1.0f - a) * (1.0f + a), 1e-6f));
        h = fmaf(a, h, gate * ix);
        se += e;
    }
    const int sidx = (b * NC + c) * D_ + d;
    P[sidx]  = exp2f(se);
    HE[sidx] = h;
}

// ---------------------------------------------------------------------------
// K3: sequential combine over NC chunks per (b,d); seeds with h0.
// ---------------------------------------------------------------------------
__global__ __launch_bounds__(256) void rg_combine(
    const float* __restrict__ P, const float* __restrict__ HE,
    const float* __restrict__ H0, float* __restrict__ CI,
    float* __restrict__ HF)
{
    const int g = blockIdx.x * 256 + threadIdx.x;   // < B*D = 8192
    const int d = g & (D_ - 1);
    const int b = g >> 10;
    float carry = H0[g];
    #pragma unroll
    for (int c = 0; c < NC; ++c) {
        const int sidx = (b * NC + c) * D_ + d;
        CI[sidx] = carry;
        carry = fmaf(P[sidx], carry, HE[sidx]);
    }
    HF[g] = carry;
}

// ---------------------------------------------------------------------------
// K4: final intra-chunk scan with correct carry; writes h_t to OUT (write-only).
// ---------------------------------------------------------------------------
__global__ __launch_bounds__(256) void rg_scan_final(
    const uint32_t* __restrict__ EIX, const float* __restrict__ CI,
    float* __restrict__ OUT)
{
    const int g = blockIdx.x * 256 + threadIdx.x;   // < B*NC*D
    const int d = g & (D_ - 1);
    const int c = (g >> 10) & (NC - 1);
    const int b = g >> 15;
    const size_t base = ((size_t)(b * T_ + c * CL)) * D_ + d;

    float h = CI[(b * NC + c) * D_ + d];
    #pragma unroll 8
    for (int t = 0; t < CL; ++t) {
        const size_t idx = base + (size_t)t * D_;
        const uint32_t u = EIX[idx];
        const float e  = bfbits2f(u << 16);
        const float ix = bfbits2f(u & 0xffff0000u);
        const float a  = exp2f(e);
        const float gate = sqrtf(fmaxf((1.0f - a) * (1.0f + a), 1e-6f));
        h = fmaf(a, h, gate * ix);
        OUT[idx] = h;
    }
}

// ---------------------------------------------------------------------------
extern "C" void kernel_launch(void* const* d_in, const int* in_sizes, int n_in,
                              void* d_out, int out_size, void* d_ws, size_t ws_size,
                              hipStream_t stream)
{
    (void)in_sizes; (void)n_in; (void)out_size; (void)ws_size;
    const float* X  = (const float*)d_in[0];
    const float* H0 = (const float*)d_in[1];
    const float* Wa = (const float*)d_in[2];
    const float* Ba = (const float*)d_in[3];
    const float* Wx = (const float*)d_in[4];
    const float* Bx = (const float*)d_in[5];
    const float* LL = (const float*)d_in[6];

    // d_out doubles as scratch for the bf16-converted operands (dead before K4
    // rewrites every output element):
    //   [0,64MB)    Xsw   (bf16, fragment-major k-chunked)
    //   [64,66MB)   Wasw  [66,68MB) Wxsw
    char* ob = (char*)d_out;
    __bf16* Xsw  = (__bf16*)ob;
    __bf16* Wasw = (__bf16*)(ob + ((size_t)M_ * K_ * 2));
    __bf16* Wxsw = (__bf16*)(ob + ((size_t)M_ * K_ * 2) + (size_t)K_ * D_ * 2);
    float*  OUT  = (float*)d_out;
    float*  HFINAL = OUT + (size_t)M_ * D_;    // h_final after outputs

    // ws: EIX (uint32, 128MB) | P | HE | CI (1MB each)  = 131 MB
    char* ws = (char*)d_ws;
    uint32_t* EIX = (uint32_t*)ws;
    float* P  = (float*)(ws + (size_t)M_ * D_ * 4);
    float* HE = P  + (size_t)B_ * NC * D_;
    float* CI = HE + (size_t)B_ * NC * D_;

    cvt_frag<<<dim3(8192 + 512), dim3(256), 0, stream>>>(
        X, Wa, Wx, Xsw, Wasw, Wxsw);

    rg_gemm_gate<<<dim3((M_/BM) * (D_/BN)), dim3(512), 0, stream>>>(
        Xsw, Wasw, Wxsw, Ba, Bx, LL, EIX);

    rg_scan_chunks<<<dim3(B_ * NC * D_ / 256), dim3(256), 0, stream>>>(EIX, P, HE);
    rg_combine<<<dim3(B_ * D_ / 256), dim3(256), 0, stream>>>(P, HE, H0, CI, HFINAL);
    rg_scan_final<<<dim3(B_ * NC * D_ / 256), dim3(256), 0, stream>>>(EIX, CI, OUT);
}